// Round 14
// baseline (909.898 us; speedup 1.0000x reference)
//
#include <hip/hip_runtime.h>

#define S_TOK 32768
#define DIN   2048
#define NH    8
#define NG    4
#define DH    128
#define NSINK 16
#define BK    64

typedef float        f32x4 __attribute__((ext_vector_type(4)));
typedef short        s16x8 __attribute__((ext_vector_type(8)));
typedef unsigned int u32x4 __attribute__((ext_vector_type(4)));

#define UR _Pragma("unroll")

__device__ __forceinline__ unsigned short f2bf(float f) {
    unsigned int u = __builtin_bit_cast(unsigned int, f);
    u = (u + 0x7fffu + ((u >> 16) & 1u)) >> 16;
    return (unsigned short)u;
}
__device__ __forceinline__ float bf2f(unsigned short h) {
    unsigned int u = ((unsigned int)h) << 16;
    return __builtin_bit_cast(float, u);
}
__device__ __forceinline__ unsigned int pack2(float lo, float hi) {
    return (unsigned int)f2bf(lo) | ((unsigned int)f2bf(hi) << 16);
}

// ---------------- fused fp32 -> bf16 pre-conversion (3 segments, 1 launch)
__global__ __launch_bounds__(256) void cvt_all_kernel(const float* __restrict__ hid,
                                                      const float* __restrict__ wq,
                                                      const float* __restrict__ wk,
                                                      unsigned short* __restrict__ ohid,
                                                      unsigned short* __restrict__ owq,
                                                      unsigned short* __restrict__ owk)
{
    const float* in;
    unsigned short* out;
    int n8, i, stride;
    if (blockIdx.x < 2048) {
        in = hid; out = ohid; n8 = (S_TOK * DIN) / 8;
        i = blockIdx.x * 256 + threadIdx.x; stride = 2048 * 256;
    } else if (blockIdx.x < 2560) {
        in = wq; out = owq; n8 = (NH * NG * DH * DIN) / 8;
        i = (blockIdx.x - 2048) * 256 + threadIdx.x; stride = 512 * 256;
    } else {
        in = wk; out = owk; n8 = (NH * DH * DIN) / 8;
        i = (blockIdx.x - 2560) * 256 + threadIdx.x; stride = 256 * 256;
    }
    for (; i < n8; i += stride) {
        const float* p = in + (size_t)i * 8;
        float4 a = *(const float4*)p;
        float4 b = *(const float4*)(p + 4);
        u32x4 v;
        v.x = pack2(a.x, a.y); v.y = pack2(a.z, a.w);
        v.z = pack2(b.x, b.y); v.w = pack2(b.z, b.w);
        *(u32x4*)(out + (size_t)i * 8) = v;
    }
}

// ---------------- Kernel A (R13-proven, frozen): k-proj 256x256 tile
__global__ __launch_bounds__(512, 2) void kproj256_bf16(const unsigned short* __restrict__ hid,
                                                        const unsigned short* __restrict__ Wk,
                                                        const float* __restrict__ knw,
                                                        unsigned short* __restrict__ kn_ws)
{
    __shared__ alignas(16) unsigned short smem[65536];
    __shared__ float wsm[128];
    unsigned short (*qsc)[132] = (unsigned short(*)[132])smem;

    const int tid = threadIdx.x, lane = tid & 63, wv = tid >> 6;
    const int wm = wv >> 2, wn = wv & 3;
    const int nt = blockIdx.x;
    const int m0 = blockIdx.y * 256;
    const int n0 = nt * 256;

    if (tid < 128) wsm[tid] = knw[tid];

    const int srow = tid >> 3;
    const int so0 = srow * DIN + (((tid & 7) ^ (srow & 7)) * 8);

    const int l15 = lane & 15;
    const int slotA = ((lane >> 4) ^ (lane & 7)) * 8;
    const int aOff0 = (wm * 128 + l15) * 64 + slotA;
    const int aOff1 = aOff0 ^ 32;
    const int bOff0 = (wn * 64 + l15) * 64 + slotA;
    const int bOff1 = bOff0 ^ 32;

    const unsigned short* aStage = hid + (size_t)m0 * DIN;
    const unsigned short* bStage = Wk + (size_t)n0 * DIN;

    f32x4 acc[8][4];
    UR for (int m = 0; m < 8; ++m)
        UR for (int n = 0; n < 4; ++n)
            acc[m][n] = f32x4{0.f, 0.f, 0.f, 0.f};

    s16x8 aF[4][2], bF[4][2];

#define GL(LDSB, SRC)                                                                              \
    __builtin_amdgcn_global_load_lds(                                                              \
        (const __attribute__((address_space(1))) unsigned int*)((SRC) + so0),                      \
        (__attribute__((address_space(3))) unsigned int*)(smem + (LDSB) + tid * 8), 16, 0, 0);     \
    __builtin_amdgcn_global_load_lds(                                                              \
        (const __attribute__((address_space(1))) unsigned int*)((SRC) + so0 + 64 * DIN),           \
        (__attribute__((address_space(3))) unsigned int*)(smem + (LDSB) + 4096 + tid * 8), 16, 0, 0);

#define GLALL(BUFW)                                                                                \
    { GL((BUFW) + 0,     aStage)             GL((BUFW) + 8192,  aStage + 128 * DIN)                \
      GL((BUFW) + 16384, bStage)             GL((BUFW) + 24576, bStage + 128 * DIN) }

#define LDA(BUF, QH)                                                                               \
    { UR for (int i_ = 0; i_ < 4; ++i_) {                                                          \
        aF[i_][0] = *(const s16x8*)&smem[(BUF) + aOff0 + ((QH) * 4 + i_) * 1024];                  \
        aF[i_][1] = *(const s16x8*)&smem[(BUF) + aOff1 + ((QH) * 4 + i_) * 1024]; } }

#define LDB(BUF, NH2)                                                                              \
    { UR for (int j_ = 0; j_ < 2; ++j_) {                                                          \
        bF[(NH2) * 2 + j_][0] = *(const s16x8*)&smem[(BUF) + 16384 + bOff0 + ((NH2) * 2 + j_) * 1024]; \
        bF[(NH2) * 2 + j_][1] = *(const s16x8*)&smem[(BUF) + 16384 + bOff1 + ((NH2) * 2 + j_) * 1024]; } }

#define MFMAQ(MF0, NF0)                                                                            \
    { __builtin_amdgcn_s_setprio(1);                                                               \
      UR for (int i_ = 0; i_ < 4; ++i_)                                                            \
        UR for (int j_ = 0; j_ < 2; ++j_)                                                          \
          UR for (int k_ = 0; k_ < 2; ++k_)                                                        \
            acc[(MF0) + i_][(NF0) + j_] = __builtin_amdgcn_mfma_f32_16x16x32_bf16(                 \
                aF[i_][k_], bF[(NF0) + j_][k_], acc[(MF0) + i_][(NF0) + j_], 0, 0, 0);             \
      __builtin_amdgcn_s_setprio(0); }

#define TILE(BUFR, BUFW, DOSTAGE)                                                                  \
    {                                                                                              \
        LDA(BUFR, 0); LDB(BUFR, 0);                                                                \
        if (DOSTAGE) { GLALL(BUFW); aStage += BK; bStage += BK; }                                  \
        MFMAQ(0, 0);                                                                               \
        LDB(BUFR, 1);                                                                              \
        MFMAQ(0, 2);                                                                               \
        LDA(BUFR, 1);                                                                              \
        MFMAQ(4, 2);                                                                               \
        MFMAQ(4, 0);                                                                               \
        asm volatile("s_waitcnt vmcnt(0)" ::: "memory");                                           \
        asm volatile("s_barrier" ::: "memory");                                                    \
    }

    GLALL(0)
    aStage += BK; bStage += BK;
    asm volatile("s_waitcnt vmcnt(0)" ::: "memory");
    asm volatile("s_barrier" ::: "memory");

    for (int i = 0; i < 15; ++i) {
        TILE(0, 32768, 1);
        TILE(32768, 0, 1);
    }
    TILE(0, 32768, 1);
    TILE(32768, 0, 0);

#undef GL
#undef GLALL
#undef LDA
#undef LDB
#undef MFMAQ
#undef TILE

    for (int c = 0; c < 2; ++c) {
        if (((wv >> 1) & 1) == c) {
            UR for (int mf = 0; mf < 8; ++mf)
                UR for (int nf = 0; nf < 4; ++nf)
                    UR for (int r = 0; r < 4; ++r)
                        qsc[wm * 128 + mf * 16 + (lane >> 4) * 4 + r][(wv & 1) * 64 + nf * 16 + l15] =
                            f2bf(acc[mf][nf][r]);
        }
        __syncthreads();

        {
            const int r2 = tid >> 1, ch = (tid & 1) * 64;
            const unsigned short* row = &qsc[r2][ch];
            float s2 = 0.f;
            UR for (int dw = 0; dw < 32; ++dw) {
                unsigned int v = *(const unsigned int*)&row[dw * 2];
                float f0 = bf2f((unsigned short)(v & 0xffff));
                float f1 = bf2f((unsigned short)(v >> 16));
                s2 += f0 * f0 + f1 * f1;
            }
            s2 += __shfl_xor(s2, 1);
            const float rq = rsqrtf(s2 * (1.0f / 128.0f) + 1e-6f);

            const int hc = nt * 2 + c;
            unsigned short* dst = kn_ws + (size_t)(m0 + r2) * (NH * DH) + hc * DH + ch;
            UR for (int i = 0; i < 8; ++i) {
                u32x4 v;
                float f0, f1;
                f0 = bf2f(row[i * 8 + 0]) * rq * wsm[ch + i * 8 + 0];
                f1 = bf2f(row[i * 8 + 1]) * rq * wsm[ch + i * 8 + 1];
                v.x = pack2(f0, f1);
                f0 = bf2f(row[i * 8 + 2]) * rq * wsm[ch + i * 8 + 2];
                f1 = bf2f(row[i * 8 + 3]) * rq * wsm[ch + i * 8 + 3];
                v.y = pack2(f0, f1);
                f0 = bf2f(row[i * 8 + 4]) * rq * wsm[ch + i * 8 + 4];
                f1 = bf2f(row[i * 8 + 5]) * rq * wsm[ch + i * 8 + 5];
                v.z = pack2(f0, f1);
                f0 = bf2f(row[i * 8 + 6]) * rq * wsm[ch + i * 8 + 6];
                f1 = bf2f(row[i * 8 + 7]) * rq * wsm[ch + i * 8 + 7];
                v.w = pack2(f0, f1);
                *(u32x4*)(dst + i * 8) = v;
            }
        }
        __syncthreads();
    }
}

// ---------------- Kernel B (R14): 256x256 block-tile, 4 waves x (128x128 wave-tile).
// Same coarse R8 schedule (1 drain+barrier per K-tile). LDS frag traffic per tile:
// 4x(128+128)x64x2B = 131 KB vs R8's 196 KB (A re-read 2x not 4x) -> LDS-BW ceiling
// rises from ~42% to ~55-60% MfmaUtil. acc[8][8]=256 VGPR -> 1 wave/SIMD
// (launch_bounds(256,1); no-spill budget ~450 per m08).
__global__ __launch_bounds__(256, 1) void qscore_bf16(const unsigned short* __restrict__ hid,
                                                      const unsigned short* __restrict__ Wq,
                                                      const float* __restrict__ bq,
                                                      const float* __restrict__ qnw,
                                                      const float* __restrict__ bb,
                                                      const float* __restrict__ kbase,
                                                      const unsigned short* __restrict__ kn_ws,
                                                      float* __restrict__ out)
{
    __shared__ alignas(16) unsigned short smem[65536];      // 2 x 64KB staging; qsc aliases after loop
    __shared__ alignas(16) unsigned short kbn[NSINK][136];
    __shared__ float rms_l[256];
    __shared__ float l_l[256];
    __shared__ float wsm[128];
    unsigned short (*qsc)[132] = (unsigned short(*)[132])smem;

    const int tid = threadIdx.x, lane = tid & 63, wv = tid >> 6;   // 4 waves
    const int wm = wv >> 1, wn = wv & 1;          // 2M x 2N wave grid; wave owns 128x128
    const int nt = blockIdx.x;                    // n-tile 0..15
    const int m0 = blockIdx.y * 256;
    const int n0 = nt * 256;
    const int h  = nt >> 1;

    if (tid < 128) wsm[tid] = qnw[tid];
    {
        const int ts = tid >> 4, d0 = (tid & 15) * 8;
        const float* src = kbase + ((size_t)h * NSINK + ts) * DH + d0;
        float4 x = *(const float4*)src;
        float4 y = *(const float4*)(src + 4);
        const float* w = qnw + d0;
        u32x4 v;
        v.x = pack2(x.x * w[0], x.y * w[1]);
        v.y = pack2(x.z * w[2], x.w * w[3]);
        v.z = pack2(y.x * w[4], y.y * w[5]);
        v.w = pack2(y.z * w[6], y.w * w[7]);
        *(u32x4*)&kbn[ts][d0] = v;
    }

    // staging (256 threads): thread covers 16B at row tid>>3 (32 rows/load), slot tid&7;
    // 8 loads per 256-row matrix, source granule pre-swizzled (slot s holds g = s^(row&7))
    const int srow = tid >> 3;
    const int so0 = srow * DIN + (((tid & 7) ^ (srow & 7)) * 8);

    const int l15 = lane & 15;
    const int slotA = ((lane >> 4) ^ (lane & 7)) * 8;
    const int aOff0 = (wm * 128 + l15) * 64 + slotA;
    const int aOff1 = aOff0 ^ 32;
    const int bOff0 = (wn * 128 + l15) * 64 + slotA;
    const int bOff1 = bOff0 ^ 32;

    const unsigned short* aStage = hid + (size_t)m0 * DIN;
    const unsigned short* bStage = Wq + (size_t)n0 * DIN;

    f32x4 acc[8][8];
    UR for (int m = 0; m < 8; ++m)
        UR for (int n = 0; n < 8; ++n)
            acc[m][n] = f32x4{0.f, 0.f, 0.f, 0.f};

    s16x8 aF[4][2], bF[8][2];

#define GL8(LDSB, SRC)                                                                             \
    { UR for (int j_ = 0; j_ < 8; ++j_)                                                            \
        __builtin_amdgcn_global_load_lds(                                                          \
            (const __attribute__((address_space(1))) unsigned int*)((SRC) + so0 + j_ * 32 * DIN),  \
            (__attribute__((address_space(3))) unsigned int*)(smem + (LDSB) + j_ * 2048 + tid * 8),\
            16, 0, 0); }

#define GLALL(BUFW)                                                                                \
    { GL8((BUFW) + 0,     aStage)  GL8((BUFW) + 16384, bStage) }

#define LDA(BUF, MH)                                                                               \
    { UR for (int i_ = 0; i_ < 4; ++i_) {                                                          \
        aF[i_][0] = *(const s16x8*)&smem[(BUF) + aOff0 + ((MH) * 4 + i_) * 1024];                  \
        aF[i_][1] = *(const s16x8*)&smem[(BUF) + aOff1 + ((MH) * 4 + i_) * 1024]; } }

#define LDBALL(BUF)                                                                                \
    { UR for (int j_ = 0; j_ < 8; ++j_) {                                                          \
        bF[j_][0] = *(const s16x8*)&smem[(BUF) + 16384 + bOff0 + j_ * 1024];                       \
        bF[j_][1] = *(const s16x8*)&smem[(BUF) + 16384 + bOff1 + j_ * 1024]; } }

#define MMH(MH)                                                                                    \
    { __builtin_amdgcn_s_setprio(1);                                                               \
      UR for (int i_ = 0; i_ < 4; ++i_)                                                            \
        UR for (int j_ = 0; j_ < 8; ++j_)                                                          \
          UR for (int k_ = 0; k_ < 2; ++k_)                                                        \
            acc[(MH) * 4 + i_][j_] = __builtin_amdgcn_mfma_f32_16x16x32_bf16(                      \
                aF[i_][k_], bF[j_][k_], acc[(MH) * 4 + i_][j_], 0, 0, 0);                          \
      __builtin_amdgcn_s_setprio(0); }

#define TILE(BUFR, BUFW, DOSTAGE)                                                                  \
    {                                                                                              \
        LDA(BUFR, 0); LDBALL(BUFR);                                                                \
        if (DOSTAGE) { GLALL(BUFW); aStage += BK; bStage += BK; }                                  \
        MMH(0);                                                                                    \
        LDA(BUFR, 1);                                                                              \
        MMH(1);                                                                                    \
        asm volatile("s_waitcnt vmcnt(0)" ::: "memory");                                           \
        asm volatile("s_barrier" ::: "memory");                                                    \
    }

    GLALL(0)
    aStage += BK; bStage += BK;
    asm volatile("s_waitcnt vmcnt(0)" ::: "memory");
    asm volatile("s_barrier" ::: "memory");

    for (int i = 0; i < 15; ++i) {
        TILE(0, 32768, 1);
        TILE(32768, 0, 1);
    }
    TILE(0, 32768, 1);
    TILE(32768, 0, 0);

#undef GL8
#undef GLALL
#undef LDA
#undef LDBALL
#undef MMH
#undef TILE

    __syncthreads();

    // ---- epilogue: two chunk-rounds; chunk c (block cols c*128..+127) is wave col-range wn==c
    float bqv[8];
    UR for (int nf = 0; nf < 8; ++nf)
        bqv[nf] = bq[n0 + wn * 128 + nf * 16 + l15];

    for (int c = 0; c < 2; ++c) {
        if (wn == c) {
            UR for (int mf = 0; mf < 8; ++mf)
                UR for (int nf = 0; nf < 8; ++nf)
                    UR for (int r = 0; r < 4; ++r)
                        qsc[wm * 128 + mf * 16 + (lane >> 4) * 4 + r][nf * 16 + l15] =
                            f2bf(acc[mf][nf][r] + bqv[nf]);
        }
        __syncthreads();

        const float bvalc = 2.0f * bb[h * NG + ((nt * 2 + c) & 3)];
        // pass2: 2 threads per row, 2 row-halves (256 rows, 256 threads)
        UR for (int rh = 0; rh < 2; ++rh) {
            const int r2 = rh * 128 + (tid >> 1), ch = (tid & 1) * 64;
            const unsigned short* qrow = &qsc[r2][ch];
            const unsigned short* kg = kn_ws + (size_t)(m0 + r2) * (NH * DH) + h * DH + ch;
            const float* wp = &wsm[ch];
            float s2 = 0.f, skq = 0.f;
            UR for (int i = 0; i < 8; ++i) {
                u32x4 kv = *(const u32x4*)(kg + i * 8);
                UR for (int j = 0; j < 4; ++j) {
                    unsigned int qv = *(const unsigned int*)&qrow[i * 8 + j * 2];
                    unsigned int kw = kv[j];
                    float q0 = bf2f((unsigned short)(qv & 0xffff));
                    float q1 = bf2f((unsigned short)(qv >> 16));
                    float k0 = bf2f((unsigned short)(kw & 0xffff));
                    float k1 = bf2f((unsigned short)(kw >> 16));
                    s2  += q0 * q0 + q1 * q1;
                    skq += q0 * k0 * wp[i * 8 + j * 2] + q1 * k1 * wp[i * 8 + j * 2 + 1];
                }
            }
            s2  += __shfl_xor(s2, 1);
            skq += __shfl_xor(skq, 1);
            if ((tid & 1) == 0) {
                const float rs = rsqrtf(s2 * (1.0f / 128.0f) + 1e-6f) * 0.08838834764831845f;
                rms_l[r2] = rs;
                l_l[r2]   = skq * rs + bvalc;
            }
        }
        __syncthreads();

        // pass3 (MFMA sink logits): 4 waves x 2 iters cover 256 rows (32 rows per iter)
        UR for (int it = 0; it < 2; ++it) {
            f32x4 sacc0 = f32x4{0.f, 0.f, 0.f, 0.f};
            f32x4 sacc1 = f32x4{0.f, 0.f, 0.f, 0.f};
            const int rb = wv * 64 + it * 32;
            const int ar = rb + l15;
            const int kc = (lane >> 4) * 8;
            UR for (int ks = 0; ks < 4; ++ks) {
                s16x8 bf_ = *(const s16x8*)&kbn[l15][ks * 32 + kc];
                s16x8 a0  = *(const s16x8*)&qsc[ar][ks * 32 + kc];
                s16x8 a1  = *(const s16x8*)&qsc[ar + 16][ks * 32 + kc];
                sacc0 = __builtin_amdgcn_mfma_f32_16x16x32_bf16(a0, bf_, sacc0, 0, 0, 0);
                sacc1 = __builtin_amdgcn_mfma_f32_16x16x32_bf16(a1, bf_, sacc1, 0, 0, 0);
            }
            UR for (int mt = 0; mt < 2; ++mt) {
                f32x4 sa = mt ? sacc1 : sacc0;
                UR for (int r = 0; r < 4; ++r) {
                    const int row = rb + mt * 16 + (lane >> 4) * 4 + r;
                    float e = __expf(sa[r] * rms_l[row] - l_l[row]);
                    e += __shfl_xor(e, 1);
                    e += __shfl_xor(e, 2);
                    e += __shfl_xor(e, 4);
                    e += __shfl_xor(e, 8);
                    if (l15 == 0)
                        atomicAdd(&out[(size_t)h * S_TOK + m0 + row], 0.25f / (1.0f + e));
                }
            }
        }
        __syncthreads();
    }
}

extern "C" void kernel_launch(void* const* d_in, const int* in_sizes, int n_in,
                              void* d_out, int out_size, void* d_ws, size_t ws_size,
                              hipStream_t stream)
{
    const float* hid = (const float*)d_in[0];
    const float* Wq  = (const float*)d_in[1];
    const float* bq  = (const float*)d_in[2];
    const float* Wk  = (const float*)d_in[3];
    const float* qnw = (const float*)d_in[4];
    const float* knw = (const float*)d_in[5];
    const float* bb  = (const float*)d_in[6];
    const float* kb  = (const float*)d_in[7];
    float* out = (float*)d_out;

    (void)hipMemsetAsync(d_out, 0, (size_t)out_size * sizeof(float), stream);

    const size_t HID_E = (size_t)S_TOK * DIN;
    const size_t WQ_E  = (size_t)NH * NG * DH * DIN;
    const size_t WK_E  = (size_t)NH * DH * DIN;

    unsigned short* hid_b = (unsigned short*)d_ws;
    unsigned short* wq_b  = hid_b + HID_E;
    unsigned short* wk_b  = wq_b + WQ_E;
    unsigned short* kn_ws = wk_b + WK_E;

    cvt_all_kernel<<<2816, 256, 0, stream>>>(hid, Wq, Wk, hid_b, wq_b, wk_b);

    kproj256_bf16<<<dim3(4, S_TOK / 256), dim3(512), 0, stream>>>(hid_b, wk_b, knw, kn_ws);
    qscore_bf16<<<dim3(NH * NG / 2, S_TOK / 256), dim3(256), 0, stream>>>(hid_b, wq_b, bq, qnw, bb, kb, kn_ws, out);
}

// Round 15
// 749.266 us; speedup vs baseline: 1.2144x; 1.2144x over previous
//
#include <hip/hip_runtime.h>

#define S_TOK 32768
#define DIN   2048
#define NH    8
#define NG    4
#define DH    128
#define NSINK 16
#define BK    64

typedef float        f32x4 __attribute__((ext_vector_type(4)));
typedef short        s16x8 __attribute__((ext_vector_type(8)));
typedef unsigned int u32x4 __attribute__((ext_vector_type(4)));

#define UR _Pragma("unroll")

__device__ __forceinline__ unsigned short f2bf(float f) {
    unsigned int u = __builtin_bit_cast(unsigned int, f);
    u = (u + 0x7fffu + ((u >> 16) & 1u)) >> 16;
    return (unsigned short)u;
}
__device__ __forceinline__ float bf2f(unsigned short h) {
    unsigned int u = ((unsigned int)h) << 16;
    return __builtin_bit_cast(float, u);
}
__device__ __forceinline__ unsigned int pack2(float lo, float hi) {
    return (unsigned int)f2bf(lo) | ((unsigned int)f2bf(hi) << 16);
}

// ---------------- fused fp32 -> bf16 pre-conversion (3 segments, 1 launch)
__global__ __launch_bounds__(256) void cvt_all_kernel(const float* __restrict__ hid,
                                                      const float* __restrict__ wq,
                                                      const float* __restrict__ wk,
                                                      unsigned short* __restrict__ ohid,
                                                      unsigned short* __restrict__ owq,
                                                      unsigned short* __restrict__ owk)
{
    const float* in;
    unsigned short* out;
    int n8, i, stride;
    if (blockIdx.x < 2048) {
        in = hid; out = ohid; n8 = (S_TOK * DIN) / 8;
        i = blockIdx.x * 256 + threadIdx.x; stride = 2048 * 256;
    } else if (blockIdx.x < 2560) {
        in = wq; out = owq; n8 = (NH * NG * DH * DIN) / 8;
        i = (blockIdx.x - 2048) * 256 + threadIdx.x; stride = 512 * 256;
    } else {
        in = wk; out = owk; n8 = (NH * DH * DIN) / 8;
        i = (blockIdx.x - 2560) * 256 + threadIdx.x; stride = 256 * 256;
    }
    for (; i < n8; i += stride) {
        const float* p = in + (size_t)i * 8;
        float4 a = *(const float4*)p;
        float4 b = *(const float4*)(p + 4);
        u32x4 v;
        v.x = pack2(a.x, a.y); v.y = pack2(a.z, a.w);
        v.z = pack2(b.x, b.y); v.w = pack2(b.z, b.w);
        *(u32x4*)(out + (size_t)i * 8) = v;
    }
}

// ---------------- Kernel A (R13-proven): k-proj 256x256 tile
__global__ __launch_bounds__(512, 2) void kproj256_bf16(const unsigned short* __restrict__ hid,
                                                        const unsigned short* __restrict__ Wk,
                                                        const float* __restrict__ knw,
                                                        unsigned short* __restrict__ kn_ws)
{
    __shared__ alignas(16) unsigned short smem[65536];
    __shared__ float wsm[128];
    unsigned short (*qsc)[132] = (unsigned short(*)[132])smem;

    const int tid = threadIdx.x, lane = tid & 63, wv = tid >> 6;
    const int wm = wv >> 2, wn = wv & 3;
    const int nt = blockIdx.x;
    const int m0 = blockIdx.y * 256;
    const int n0 = nt * 256;

    if (tid < 128) wsm[tid] = knw[tid];

    const int srow = tid >> 3;
    const int so0 = srow * DIN + (((tid & 7) ^ (srow & 7)) * 8);

    const int l15 = lane & 15;
    const int slotA = ((lane >> 4) ^ (lane & 7)) * 8;
    const int aOff0 = (wm * 128 + l15) * 64 + slotA;
    const int aOff1 = aOff0 ^ 32;
    const int bOff0 = (wn * 64 + l15) * 64 + slotA;
    const int bOff1 = bOff0 ^ 32;

    const unsigned short* aStage = hid + (size_t)m0 * DIN;
    const unsigned short* bStage = Wk + (size_t)n0 * DIN;

    f32x4 acc[8][4];
    UR for (int m = 0; m < 8; ++m)
        UR for (int n = 0; n < 4; ++n)
            acc[m][n] = f32x4{0.f, 0.f, 0.f, 0.f};

    s16x8 aF[4][2], bF[4][2];

#define GL(LDSB, SRC)                                                                              \
    __builtin_amdgcn_global_load_lds(                                                              \
        (const __attribute__((address_space(1))) unsigned int*)((SRC) + so0),                      \
        (__attribute__((address_space(3))) unsigned int*)(smem + (LDSB) + tid * 8), 16, 0, 0);     \
    __builtin_amdgcn_global_load_lds(                                                              \
        (const __attribute__((address_space(1))) unsigned int*)((SRC) + so0 + 64 * DIN),           \
        (__attribute__((address_space(3))) unsigned int*)(smem + (LDSB) + 4096 + tid * 8), 16, 0, 0);

#define GLALL(BUFW)                                                                                \
    { GL((BUFW) + 0,     aStage)             GL((BUFW) + 8192,  aStage + 128 * DIN)                \
      GL((BUFW) + 16384, bStage)             GL((BUFW) + 24576, bStage + 128 * DIN) }

#define LDA(BUF, QH)                                                                               \
    { UR for (int i_ = 0; i_ < 4; ++i_) {                                                          \
        aF[i_][0] = *(const s16x8*)&smem[(BUF) + aOff0 + ((QH) * 4 + i_) * 1024];                  \
        aF[i_][1] = *(const s16x8*)&smem[(BUF) + aOff1 + ((QH) * 4 + i_) * 1024]; } }

#define LDB(BUF, NH2)                                                                              \
    { UR for (int j_ = 0; j_ < 2; ++j_) {                                                          \
        bF[(NH2) * 2 + j_][0] = *(const s16x8*)&smem[(BUF) + 16384 + bOff0 + ((NH2) * 2 + j_) * 1024]; \
        bF[(NH2) * 2 + j_][1] = *(const s16x8*)&smem[(BUF) + 16384 + bOff1 + ((NH2) * 2 + j_) * 1024]; } }

#define MFMAQ(MF0, NF0)                                                                            \
    { __builtin_amdgcn_s_setprio(1);                                                               \
      UR for (int i_ = 0; i_ < 4; ++i_)                                                            \
        UR for (int j_ = 0; j_ < 2; ++j_)                                                          \
          UR for (int k_ = 0; k_ < 2; ++k_)                                                        \
            acc[(MF0) + i_][(NF0) + j_] = __builtin_amdgcn_mfma_f32_16x16x32_bf16(                 \
                aF[i_][k_], bF[(NF0) + j_][k_], acc[(MF0) + i_][(NF0) + j_], 0, 0, 0);             \
      __builtin_amdgcn_s_setprio(0); }

#define TILE(BUFR, BUFW, DOSTAGE)                                                                  \
    {                                                                                              \
        LDA(BUFR, 0); LDB(BUFR, 0);                                                                \
        if (DOSTAGE) { GLALL(BUFW); aStage += BK; bStage += BK; }                                  \
        MFMAQ(0, 0);                                                                               \
        LDB(BUFR, 1);                                                                              \
        MFMAQ(0, 2);                                                                               \
        LDA(BUFR, 1);                                                                              \
        MFMAQ(4, 2);                                                                               \
        MFMAQ(4, 0);                                                                               \
        asm volatile("s_waitcnt vmcnt(0)" ::: "memory");                                           \
        asm volatile("s_barrier" ::: "memory");                                                    \
    }

    GLALL(0)
    aStage += BK; bStage += BK;
    asm volatile("s_waitcnt vmcnt(0)" ::: "memory");
    asm volatile("s_barrier" ::: "memory");

    for (int i = 0; i < 15; ++i) {
        TILE(0, 32768, 1);
        TILE(32768, 0, 1);
    }
    TILE(0, 32768, 1);
    TILE(32768, 0, 0);

#undef GL
#undef GLALL
#undef LDA
#undef LDB
#undef MFMAQ
#undef TILE

    for (int c = 0; c < 2; ++c) {
        if (((wv >> 1) & 1) == c) {
            UR for (int mf = 0; mf < 8; ++mf)
                UR for (int nf = 0; nf < 4; ++nf)
                    UR for (int r = 0; r < 4; ++r)
                        qsc[wm * 128 + mf * 16 + (lane >> 4) * 4 + r][(wv & 1) * 64 + nf * 16 + l15] =
                            f2bf(acc[mf][nf][r]);
        }
        __syncthreads();

        {
            const int r2 = tid >> 1, ch = (tid & 1) * 64;
            const unsigned short* row = &qsc[r2][ch];
            float s2 = 0.f;
            UR for (int dw = 0; dw < 32; ++dw) {
                unsigned int v = *(const unsigned int*)&row[dw * 2];
                float f0 = bf2f((unsigned short)(v & 0xffff));
                float f1 = bf2f((unsigned short)(v >> 16));
                s2 += f0 * f0 + f1 * f1;
            }
            s2 += __shfl_xor(s2, 1);
            const float rq = rsqrtf(s2 * (1.0f / 128.0f) + 1e-6f);

            const int hc = nt * 2 + c;
            unsigned short* dst = kn_ws + (size_t)(m0 + r2) * (NH * DH) + hc * DH + ch;
            UR for (int i = 0; i < 8; ++i) {
                u32x4 v;
                float f0, f1;
                f0 = bf2f(row[i * 8 + 0]) * rq * wsm[ch + i * 8 + 0];
                f1 = bf2f(row[i * 8 + 1]) * rq * wsm[ch + i * 8 + 1];
                v.x = pack2(f0, f1);
                f0 = bf2f(row[i * 8 + 2]) * rq * wsm[ch + i * 8 + 2];
                f1 = bf2f(row[i * 8 + 3]) * rq * wsm[ch + i * 8 + 3];
                v.y = pack2(f0, f1);
                f0 = bf2f(row[i * 8 + 4]) * rq * wsm[ch + i * 8 + 4];
                f1 = bf2f(row[i * 8 + 5]) * rq * wsm[ch + i * 8 + 5];
                v.z = pack2(f0, f1);
                f0 = bf2f(row[i * 8 + 6]) * rq * wsm[ch + i * 8 + 6];
                f1 = bf2f(row[i * 8 + 7]) * rq * wsm[ch + i * 8 + 7];
                v.w = pack2(f0, f1);
                *(u32x4*)(dst + i * 8) = v;
            }
        }
        __syncthreads();
    }
}

// ---------------- Kernel B (R8-proven, frozen): 256x256-tile q-proj + RMSNorm + MFMA sink gate
__global__ __launch_bounds__(512, 2) void qscore_bf16(const unsigned short* __restrict__ hid,
                                                      const unsigned short* __restrict__ Wq,
                                                      const float* __restrict__ bq,
                                                      const float* __restrict__ qnw,
                                                      const float* __restrict__ bb,
                                                      const float* __restrict__ kbase,
                                                      const unsigned short* __restrict__ kn_ws,
                                                      float* __restrict__ out)
{
    __shared__ alignas(16) unsigned short smem[65536];
    __shared__ alignas(16) unsigned short kbn[NSINK][136];
    __shared__ float rms_l[256];
    __shared__ float l_l[256];
    __shared__ float wsm[128];
    unsigned short (*qsc)[132] = (unsigned short(*)[132])smem;

    const int tid = threadIdx.x, lane = tid & 63, wv = tid >> 6;
    const int wm = wv >> 2, wn = wv & 3;
    const int nt = blockIdx.x;
    const int m0 = blockIdx.y * 256;
    const int n0 = nt * 256;
    const int h  = nt >> 1;

    if (tid < 128) wsm[tid] = qnw[tid];
    if (tid < 256) {
        const int ts = tid >> 4, d0 = (tid & 15) * 8;
        const float* src = kbase + ((size_t)h * NSINK + ts) * DH + d0;
        float4 x = *(const float4*)src;
        float4 y = *(const float4*)(src + 4);
        const float* w = qnw + d0;
        u32x4 v;
        v.x = pack2(x.x * w[0], x.y * w[1]);
        v.y = pack2(x.z * w[2], x.w * w[3]);
        v.z = pack2(y.x * w[4], y.y * w[5]);
        v.w = pack2(y.z * w[6], y.w * w[7]);
        *(u32x4*)&kbn[ts][d0] = v;
    }

    const int srow = tid >> 3;
    const int so0 = srow * DIN + (((tid & 7) ^ (srow & 7)) * 8);

    const int l15 = lane & 15;
    const int slotA = ((lane >> 4) ^ (lane & 7)) * 8;
    const int aOff0 = (wm * 128 + l15) * 64 + slotA;
    const int aOff1 = aOff0 ^ 32;
    const int bOff0 = (wn * 64 + l15) * 64 + slotA;
    const int bOff1 = bOff0 ^ 32;

    const unsigned short* aStage = hid + (size_t)m0 * DIN;
    const unsigned short* bStage = Wq + (size_t)n0 * DIN;

    f32x4 acc[8][4];
    UR for (int m = 0; m < 8; ++m)
        UR for (int n = 0; n < 4; ++n)
            acc[m][n] = f32x4{0.f, 0.f, 0.f, 0.f};

    s16x8 aF[4][2], bF[4][2];

#define GL(LDSB, SRC)                                                                              \
    __builtin_amdgcn_global_load_lds(                                                              \
        (const __attribute__((address_space(1))) unsigned int*)((SRC) + so0),                      \
        (__attribute__((address_space(3))) unsigned int*)(smem + (LDSB) + tid * 8), 16, 0, 0);     \
    __builtin_amdgcn_global_load_lds(                                                              \
        (const __attribute__((address_space(1))) unsigned int*)((SRC) + so0 + 64 * DIN),           \
        (__attribute__((address_space(3))) unsigned int*)(smem + (LDSB) + 4096 + tid * 8), 16, 0, 0);

#define GLALL(BUFW)                                                                                \
    { GL((BUFW) + 0,     aStage)             GL((BUFW) + 8192,  aStage + 128 * DIN)                \
      GL((BUFW) + 16384, bStage)             GL((BUFW) + 24576, bStage + 128 * DIN) }

#define LDA(BUF, QH)                                                                               \
    { UR for (int i_ = 0; i_ < 4; ++i_) {                                                          \
        aF[i_][0] = *(const s16x8*)&smem[(BUF) + aOff0 + ((QH) * 4 + i_) * 1024];                  \
        aF[i_][1] = *(const s16x8*)&smem[(BUF) + aOff1 + ((QH) * 4 + i_) * 1024]; } }

#define LDB(BUF, NH2)                                                                              \
    { UR for (int j_ = 0; j_ < 2; ++j_) {                                                          \
        bF[(NH2) * 2 + j_][0] = *(const s16x8*)&smem[(BUF) + 16384 + bOff0 + ((NH2) * 2 + j_) * 1024]; \
        bF[(NH2) * 2 + j_][1] = *(const s16x8*)&smem[(BUF) + 16384 + bOff1 + ((NH2) * 2 + j_) * 1024]; } }

#define MFMAQ(MF0, NF0)                                                                            \
    { __builtin_amdgcn_s_setprio(1);                                                               \
      UR for (int i_ = 0; i_ < 4; ++i_)                                                            \
        UR for (int j_ = 0; j_ < 2; ++j_)                                                          \
          UR for (int k_ = 0; k_ < 2; ++k_)                                                        \
            acc[(MF0) + i_][(NF0) + j_] = __builtin_amdgcn_mfma_f32_16x16x32_bf16(                 \
                aF[i_][k_], bF[(NF0) + j_][k_], acc[(MF0) + i_][(NF0) + j_], 0, 0, 0);             \
      __builtin_amdgcn_s_setprio(0); }

#define TILE(BUFR, BUFW, DOSTAGE)                                                                  \
    {                                                                                              \
        LDA(BUFR, 0); LDB(BUFR, 0);                                                                \
        if (DOSTAGE) { GLALL(BUFW); aStage += BK; bStage += BK; }                                  \
        MFMAQ(0, 0);                                                                               \
        LDB(BUFR, 1);                                                                              \
        MFMAQ(0, 2);                                                                               \
        LDA(BUFR, 1);                                                                              \
        MFMAQ(4, 2);                                                                               \
        MFMAQ(4, 0);                                                                               \
        asm volatile("s_waitcnt vmcnt(0)" ::: "memory");                                           \
        asm volatile("s_barrier" ::: "memory");                                                    \
    }

    GLALL(0)
    aStage += BK; bStage += BK;
    asm volatile("s_waitcnt vmcnt(0)" ::: "memory");
    asm volatile("s_barrier" ::: "memory");

    for (int i = 0; i < 15; ++i) {
        TILE(0, 32768, 1);
        TILE(32768, 0, 1);
    }
    TILE(0, 32768, 1);
    TILE(32768, 0, 0);

#undef GL
#undef GLALL
#undef LDA
#undef LDB
#undef MFMAQ
#undef TILE

    float bqv[4];
    UR for (int nf = 0; nf < 4; ++nf)
        bqv[nf] = bq[n0 + wn * 64 + nf * 16 + l15];

    for (int c = 0; c < 2; ++c) {
        if (((wv >> 1) & 1) == c) {
            UR for (int mf = 0; mf < 8; ++mf)
                UR for (int nf = 0; nf < 4; ++nf)
                    UR for (int r = 0; r < 4; ++r)
                        qsc[wm * 128 + mf * 16 + (lane >> 4) * 4 + r][(wv & 1) * 64 + nf * 16 + l15] =
                            f2bf(acc[mf][nf][r] + bqv[nf]);
        }
        __syncthreads();

        const float bvalc = 2.0f * bb[h * NG + ((nt * 2 + c) & 3)];
        {
            const int r2 = tid >> 1, ch = (tid & 1) * 64;
            const unsigned short* qrow = &qsc[r2][ch];
            const unsigned short* kg = kn_ws + (size_t)(m0 + r2) * (NH * DH) + h * DH + ch;
            const float* wp = &wsm[ch];
            float s2 = 0.f, skq = 0.f;
            UR for (int i = 0; i < 8; ++i) {
                u32x4 kv = *(const u32x4*)(kg + i * 8);
                UR for (int j = 0; j < 4; ++j) {
                    unsigned int qv = *(const unsigned int*)&qrow[i * 8 + j * 2];
                    unsigned int kw = kv[j];
                    float q0 = bf2f((unsigned short)(qv & 0xffff));
                    float q1 = bf2f((unsigned short)(qv >> 16));
                    float k0 = bf2f((unsigned short)(kw & 0xffff));
                    float k1 = bf2f((unsigned short)(kw >> 16));
                    s2  += q0 * q0 + q1 * q1;
                    skq += q0 * k0 * wp[i * 8 + j * 2] + q1 * k1 * wp[i * 8 + j * 2 + 1];
                }
            }
            s2  += __shfl_xor(s2, 1);
            skq += __shfl_xor(skq, 1);
            if ((tid & 1) == 0) {
                const float rs = rsqrtf(s2 * (1.0f / 128.0f) + 1e-6f) * 0.08838834764831845f;
                rms_l[r2] = rs;
                l_l[r2]   = skq * rs + bvalc;
            }
        }
        __syncthreads();

        {
            f32x4 sacc0 = f32x4{0.f, 0.f, 0.f, 0.f};
            f32x4 sacc1 = f32x4{0.f, 0.f, 0.f, 0.f};
            const int ar = wv * 32 + l15;
            const int kc = (lane >> 4) * 8;
            UR for (int ks = 0; ks < 4; ++ks) {
                s16x8 bf_ = *(const s16x8*)&kbn[l15][ks * 32 + kc];
                s16x8 a0  = *(const s16x8*)&qsc[ar][ks * 32 + kc];
                s16x8 a1  = *(const s16x8*)&qsc[ar + 16][ks * 32 + kc];
                sacc0 = __builtin_amdgcn_mfma_f32_16x16x32_bf16(a0, bf_, sacc0, 0, 0, 0);
                sacc1 = __builtin_amdgcn_mfma_f32_16x16x32_bf16(a1, bf_, sacc1, 0, 0, 0);
            }
            UR for (int mt = 0; mt < 2; ++mt) {
                f32x4 sa = mt ? sacc1 : sacc0;
                UR for (int r = 0; r < 4; ++r) {
                    const int row = wv * 32 + mt * 16 + (lane >> 4) * 4 + r;
                    float e = __expf(sa[r] * rms_l[row] - l_l[row]);
                    e += __shfl_xor(e, 1);
                    e += __shfl_xor(e, 2);
                    e += __shfl_xor(e, 4);
                    e += __shfl_xor(e, 8);
                    if (l15 == 0)
                        atomicAdd(&out[(size_t)h * S_TOK + m0 + row], 0.25f / (1.0f + e));
                }
            }
        }
        __syncthreads();
    }
}

extern "C" void kernel_launch(void* const* d_in, const int* in_sizes, int n_in,
                              void* d_out, int out_size, void* d_ws, size_t ws_size,
                              hipStream_t stream)
{
    const float* hid = (const float*)d_in[0];
    const float* Wq  = (const float*)d_in[1];
    const float* bq  = (const float*)d_in[2];
    const float* Wk  = (const float*)d_in[3];
    const float* qnw = (const float*)d_in[4];
    const float* knw = (const float*)d_in[5];
    const float* bb  = (const float*)d_in[6];
    const float* kb  = (const float*)d_in[7];
    float* out = (float*)d_out;

    (void)hipMemsetAsync(d_out, 0, (size_t)out_size * sizeof(float), stream);

    const size_t HID_E = (size_t)S_TOK * DIN;
    const size_t WQ_E  = (size_t)NH * NG * DH * DIN;
    const size_t WK_E  = (size_t)NH * DH * DIN;

    unsigned short* hid_b = (unsigned short*)d_ws;
    unsigned short* wq_b  = hid_b + HID_E;
    unsigned short* wk_b  = wq_b + WQ_E;
    unsigned short* kn_ws = wk_b + WK_E;

    cvt_all_kernel<<<2816, 256, 0, stream>>>(hid, Wq, Wk, hid_b, wq_b, wk_b);

    kproj256_bf16<<<dim3(4, S_TOK / 256), dim3(512), 0, stream>>>(hid_b, wk_b, knw, kn_ws);
    qscore_bf16<<<dim3(NH * NG / 2, S_TOK / 256), dim3(512), 0, stream>>>(hid_b, wq_b, bq, qnw, bb, kb, kn_ws, out);
}